// Round 7
// baseline (54.566 us; speedup 1.0000x reference)
//
#include <hip/hip_runtime.h>

// SigNet forward, closed-form (scan-free) depth-3 signature + Linear.
// B=256, L=256, CIN=8, C=9, SIG_CH=819, OUT=128.
//
// s1[i]       = x_L[i]
// s2[i][j]    = sum_l w_l[i] * d_l[j]                   w = x_{l-1} + 0.5*d
// s3[i][j][k] = s2[i][j]*x_L[k]
//             + sum_l ( z_l[i]*d_l[j]*d_l[k] - w_l[i]*d_l[j]*x_l[k] )
//   with z = 0.5*w - d/12,  x = w + 0.5*d   (only W,D tables in LDS)
//
// One block per batch, 1024 threads (16 waves/CU). 32 l-chunks x 27 threads
// own (i, all j, k-triple). x_L comes straight from global in prep (no table
// read after the main loop) so the dump region's aliasing of the dead tables
// has exactly one read->write transition, guarded by one barrier.

#define ROWF    260           // table row stride in floats (260%32==4)
#define NCHUNK  32
#define TPC     27
#define ASTRIDE 29
#define CHSTR   (TPC * ASTRIDE)                 // 783
#define DUMPF   (NCHUNK * CHSTR)                // 25056 floats
#define U1SZ    (DUMPF + NCHUNK * 81)           // 27648 floats = 110.6 KB

__global__ __launch_bounds__(1024) void signet_fwd(
    const float* __restrict__ inp,   // [256, 256, 8]
    const float* __restrict__ Wg,    // [819, 128]
    const float* __restrict__ bias,  // [128]
    float* __restrict__ out)         // [256, 128]
{
    __shared__ float sig[820];
    __shared__ __align__(16) float u[U1SZ];

    float* Wt = u;                 // [9][ROWF]   (dead after main loop)
    float* Dt = u + 9 * ROWF;      // [9][ROWF]

    const int tid = threadIdx.x;
    const int b   = blockIdx.x;

    // ---- prep: tables (column t = segment t+1, basepoint 0) + s1 = x_L ----
    if (tid < 512) {
        const int t = tid & 255;
        const float* rc = inp + (size_t)b * 2048 + (size_t)t * 8;
        if (tid < 256) {
            float4 c0 = *(const float4*)rc;
            float4 p0 = make_float4(0.f, 0.f, 0.f, 0.f);
            float  tp = 0.f;
            if (t > 0) { p0 = *(const float4*)(rc - 8); tp = (float)(t - 1) * (1.0f / 255.0f); }
            float cur[5] = { (float)t * (1.0f / 255.0f), c0.x, c0.y, c0.z, c0.w };
            float prv[5] = { tp, p0.x, p0.y, p0.z, p0.w };
            #pragma unroll
            for (int c = 0; c < 5; ++c) {
                const float d = cur[c] - prv[c];
                Dt[c * ROWF + t] = d;
                Wt[c * ROWF + t] = prv[c] + 0.5f * d;
            }
        } else {
            float4 c1 = *(const float4*)(rc + 4);
            float4 p1 = make_float4(0.f, 0.f, 0.f, 0.f);
            if (t > 0) p1 = *(const float4*)(rc - 4);
            float cur[4] = { c1.x, c1.y, c1.z, c1.w };
            float prv[4] = { p1.x, p1.y, p1.z, p1.w };
            #pragma unroll
            for (int c = 0; c < 4; ++c) {
                const float d = cur[c] - prv[c];
                Dt[(5 + c) * ROWF + t] = d;
                Wt[(5 + c) * ROWF + t] = prv[c] + 0.5f * d;
            }
        }
    }
    if (tid < 9) {
        sig[tid] = (tid == 0) ? 1.0f
                              : inp[(size_t)b * 2048 + 255 * 8 + (tid - 1)];
    }
    __syncthreads();

    // ---- main: chunk = tid/27 handles float4 cols {2*chunk, 2*chunk+1} ----
    const int  chunk = tid / TPC;            // 0..37 (>=32 idle)
    const int  tloc  = tid - chunk * TPC;    // 0..26
    const int  ci    = tloc / 3;             // channel i
    const int  kt    = tloc - ci * 3;        // k-triple
    const bool act   = (chunk < NCHUNK);

    float a[9][3];
    float s2a[9];
    #pragma unroll
    for (int j = 0; j < 9; ++j) { s2a[j] = 0.f; a[j][0] = 0.f; a[j][1] = 0.f; a[j][2] = 0.f; }

    if (act) {
        const float4* W4 = (const float4*)u;             // [9][65]
        const float4* D4 = (const float4*)u + 9 * 65;
        const int k0 = 3 * kt;
        const int fb = chunk * 2;

        #pragma unroll
        for (int q = 0; q < 2; ++q) {
            const int idx = fb + q;
            const float4 w   = W4[ci * 65 + idx];
            const float4 di  = D4[ci * 65 + idx];
            const float4 Wk0 = W4[(k0 + 0) * 65 + idx];
            const float4 Wk1 = W4[(k0 + 1) * 65 + idx];
            const float4 Wk2 = W4[(k0 + 2) * 65 + idx];
            const float4 Dk0 = D4[(k0 + 0) * 65 + idx];
            const float4 Dk1 = D4[(k0 + 1) * 65 + idx];
            const float4 Dk2 = D4[(k0 + 2) * 65 + idx];

            float4 z, X0, X1, X2;
            z.x = fmaf(-(1.0f / 12.0f), di.x, 0.5f * w.x);
            z.y = fmaf(-(1.0f / 12.0f), di.y, 0.5f * w.y);
            z.z = fmaf(-(1.0f / 12.0f), di.z, 0.5f * w.z);
            z.w = fmaf(-(1.0f / 12.0f), di.w, 0.5f * w.w);
            X0.x = fmaf(0.5f, Dk0.x, Wk0.x); X0.y = fmaf(0.5f, Dk0.y, Wk0.y);
            X0.z = fmaf(0.5f, Dk0.z, Wk0.z); X0.w = fmaf(0.5f, Dk0.w, Wk0.w);
            X1.x = fmaf(0.5f, Dk1.x, Wk1.x); X1.y = fmaf(0.5f, Dk1.y, Wk1.y);
            X1.z = fmaf(0.5f, Dk1.z, Wk1.z); X1.w = fmaf(0.5f, Dk1.w, Wk1.w);
            X2.x = fmaf(0.5f, Dk2.x, Wk2.x); X2.y = fmaf(0.5f, Dk2.y, Wk2.y);
            X2.z = fmaf(0.5f, Dk2.z, Wk2.z); X2.w = fmaf(0.5f, Dk2.w, Wk2.w);

            #pragma unroll
            for (int j = 0; j < 9; ++j) {
                const float4 dj = D4[j * 65 + idx];
                { const float uu = w.x * dj.x, vv = z.x * dj.x; s2a[j] += uu;
                  a[j][0] = fmaf(vv, Dk0.x, fmaf(-uu, X0.x, a[j][0]));
                  a[j][1] = fmaf(vv, Dk1.x, fmaf(-uu, X1.x, a[j][1]));
                  a[j][2] = fmaf(vv, Dk2.x, fmaf(-uu, X2.x, a[j][2])); }
                { const float uu = w.y * dj.y, vv = z.y * dj.y; s2a[j] += uu;
                  a[j][0] = fmaf(vv, Dk0.y, fmaf(-uu, X0.y, a[j][0]));
                  a[j][1] = fmaf(vv, Dk1.y, fmaf(-uu, X1.y, a[j][1]));
                  a[j][2] = fmaf(vv, Dk2.y, fmaf(-uu, X2.y, a[j][2])); }
                { const float uu = w.z * dj.z, vv = z.z * dj.z; s2a[j] += uu;
                  a[j][0] = fmaf(vv, Dk0.z, fmaf(-uu, X0.z, a[j][0]));
                  a[j][1] = fmaf(vv, Dk1.z, fmaf(-uu, X1.z, a[j][1]));
                  a[j][2] = fmaf(vv, Dk2.z, fmaf(-uu, X2.z, a[j][2])); }
                { const float uu = w.w * dj.w, vv = z.w * dj.w; s2a[j] += uu;
                  a[j][0] = fmaf(vv, Dk0.w, fmaf(-uu, X0.w, a[j][0]));
                  a[j][1] = fmaf(vv, Dk1.w, fmaf(-uu, X1.w, a[j][1]));
                  a[j][2] = fmaf(vv, Dk2.w, fmaf(-uu, X2.w, a[j][2])); }
            }
        }
    }
    __syncthreads();   // last table read is above; dump may now alias tables

    // ---- dump partials (aliases dead tables) ----
    if (act) {
        float* pa = u + tid * ASTRIDE;
        #pragma unroll
        for (int j = 0; j < 9; ++j) {
            pa[j * 3 + 0] = a[j][0];
            pa[j * 3 + 1] = a[j][1];
            pa[j * 3 + 2] = a[j][2];
        }
        if (kt == 0) {
            float* ps = u + DUMPF + chunk * 81 + ci * 9;
            #pragma unroll
            for (int j = 0; j < 9; ++j) ps[j] = s2a[j];
        }
    }
    __syncthreads();

    // ---- combine s2 -> sig[9..89] ----
    if (tid < 81) {
        float s = 0.f;
        #pragma unroll
        for (int c = 0; c < NCHUNK; ++c) s += u[DUMPF + c * 81 + tid];
        sig[9 + tid] = s;
    }
    __syncthreads();

    // ---- combine s3 -> sig[90..818] (one element per thread) ----
    if (tid < 729) {
        const int e   = tid;
        const int i   = e / 81;
        const int r   = e - i * 81;
        const int j   = r / 9;
        const int k   = r - j * 9;
        const int ktv = k / 3;
        const int km  = k - ktv * 3;
        const int toff = (i * 3 + ktv) * ASTRIDE + j * 3 + km;
        float s = 0.f;
        #pragma unroll
        for (int c = 0; c < NCHUNK; ++c) s += u[c * CHSTR + toff];
        s = fmaf(sig[9 + i * 9 + j], sig[k], s);
        sig[90 + e] = s;
    }
    __syncthreads();

    // ---- linear: out[b][o] = bias[o] + sum_ch sig[ch]*Wg[ch][o] ----
    {
        const int oq = tid & 31;     // outputs 4*oq..4*oq+3
        const int sl = tid >> 5;     // channel slice 0..31
        float4 acc = make_float4(0.f, 0.f, 0.f, 0.f);
        const float4* Wq = (const float4*)Wg;
        for (int ch = sl; ch < 819; ch += 32) {
            const float s = sig[ch];
            const float4 wv = Wq[(size_t)ch * 32 + oq];
            acc.x = fmaf(s, wv.x, acc.x);
            acc.y = fmaf(s, wv.y, acc.y);
            acc.z = fmaf(s, wv.z, acc.z);
            acc.w = fmaf(s, wv.w, acc.w);
        }
        float4* pbuf = (float4*)u;               // aliases dead dump region
        pbuf[sl * 32 + oq] = acc;
    }
    __syncthreads();
    if (tid < 32) {
        const float4* pbuf = (const float4*)u;
        float4 r = pbuf[tid];
        #pragma unroll
        for (int s = 1; s < 32; ++s) {
            const float4 p = pbuf[s * 32 + tid];
            r.x += p.x; r.y += p.y; r.z += p.z; r.w += p.w;
        }
        const float4 bv = ((const float4*)bias)[tid];
        r.x += bv.x; r.y += bv.y; r.z += bv.z; r.w += bv.w;
        ((float4*)(out + (size_t)b * 128))[tid] = r;
    }
}

extern "C" void kernel_launch(void* const* d_in, const int* in_sizes, int n_in,
                              void* d_out, int out_size, void* d_ws, size_t ws_size,
                              hipStream_t stream) {
    const float* inp  = (const float*)d_in[0];
    const float* Wp   = (const float*)d_in[1];
    const float* bias = (const float*)d_in[2];
    float* outp = (float*)d_out;
    (void)in_sizes; (void)n_in; (void)out_size; (void)d_ws; (void)ws_size;

    hipLaunchKernelGGL(signet_fwd, dim3(256), dim3(1024), 0, stream,
                       inp, Wp, bias, outp);
}

// Round 8
// 45.330 us; speedup vs baseline: 1.2038x; 1.2038x over previous
//
#include <hip/hip_runtime.h>

// SigNet forward, closed-form (scan-free) depth-3 signature + Linear.
// B=256, L=256, CIN=8, C=9, SIG_CH=819, OUT=128.
//
// s1[i]       = x_L[i]
// s2[i][j]    = sum_l w_l[i] * d_l[j]                   w = X - 0.5*D
// s3[i][j][k] = s2[i][j]*x_L[k]
//             + sum_l ( z_l[i]*d_l[j]*d_l[k] - w_l[i]*d_l[j]*X_l[k] )
//   with z = 0.5*X - D/3       (X = absolute path value at segment end)
//
// One block per batch, 1024 threads, __launch_bounds__(1024,4) -> 128 VGPR
// cap (NO spill; R7's 64-VGPR cap spilled 36 accumulators to scratch =
// 175 MB HBM traffic). X/D tables in LDS; 32 l-chunks x 27 threads own
// (i, all j, k-triple); partials dumped to LDS aliasing the dead tables.

#define ROWF    260           // table row stride in floats (260%32==4)
#define NCHUNK  32
#define TPC     27
#define ASTRIDE 29
#define CHSTR   (TPC * ASTRIDE)                 // 783
#define DUMPF   (NCHUNK * CHSTR)                // 25056 floats
#define U1SZ    (DUMPF + NCHUNK * 81)           // 27648 floats = 110.6 KB

__global__ __launch_bounds__(1024, 4) void signet_fwd(
    const float* __restrict__ inp,   // [256, 256, 8]
    const float* __restrict__ Wg,    // [819, 128]
    const float* __restrict__ bias,  // [128]
    float* __restrict__ out)         // [256, 128]
{
    __shared__ float sig[820];
    __shared__ __align__(16) float u[U1SZ];

    float* Xt = u;                 // [9][ROWF]   (dead after main loop)
    float* Dt = u + 9 * ROWF;      // [9][ROWF]

    const int tid = threadIdx.x;
    const int b   = blockIdx.x;

    // ---- prep: tables (column t = segment t+1, basepoint 0) + s1 = x_L ----
    if (tid < 512) {
        const int t = tid & 255;
        const float* rc = inp + (size_t)b * 2048 + (size_t)t * 8;
        if (tid < 256) {
            float4 c0 = *(const float4*)rc;
            float4 p0 = make_float4(0.f, 0.f, 0.f, 0.f);
            float  tp = 0.f;
            if (t > 0) { p0 = *(const float4*)(rc - 8); tp = (float)(t - 1) * (1.0f / 255.0f); }
            float cur[5] = { (float)t * (1.0f / 255.0f), c0.x, c0.y, c0.z, c0.w };
            float prv[5] = { tp, p0.x, p0.y, p0.z, p0.w };
            #pragma unroll
            for (int c = 0; c < 5; ++c) {
                Xt[c * ROWF + t] = cur[c];
                Dt[c * ROWF + t] = cur[c] - prv[c];
            }
        } else {
            float4 c1 = *(const float4*)(rc + 4);
            float4 p1 = make_float4(0.f, 0.f, 0.f, 0.f);
            if (t > 0) p1 = *(const float4*)(rc - 4);
            float cur[4] = { c1.x, c1.y, c1.z, c1.w };
            float prv[4] = { p1.x, p1.y, p1.z, p1.w };
            #pragma unroll
            for (int c = 0; c < 4; ++c) {
                Xt[(5 + c) * ROWF + t] = cur[c];
                Dt[(5 + c) * ROWF + t] = cur[c] - prv[c];
            }
        }
    }
    if (tid < 9) {
        sig[tid] = (tid == 0) ? 1.0f
                              : inp[(size_t)b * 2048 + 255 * 8 + (tid - 1)];
    }
    __syncthreads();

    // ---- main: chunk = tid/27 handles float4 cols {2*chunk, 2*chunk+1} ----
    const int  chunk = tid / TPC;            // 0..37 (>=32 idle)
    const int  tloc  = tid - chunk * TPC;    // 0..26
    const int  ci    = tloc / 3;             // channel i
    const int  kt    = tloc - ci * 3;        // k-triple
    const bool act   = (chunk < NCHUNK);

    float a[9][3];
    float s2a[9];
    #pragma unroll
    for (int j = 0; j < 9; ++j) { s2a[j] = 0.f; a[j][0] = 0.f; a[j][1] = 0.f; a[j][2] = 0.f; }

    if (act) {
        const float4* X4 = (const float4*)u;             // [9][65]
        const float4* D4 = (const float4*)u + 9 * 65;
        const int k0 = 3 * kt;
        const int fb = chunk * 2;

        #pragma unroll
        for (int q = 0; q < 2; ++q) {
            const int idx = fb + q;
            const float4 Xi  = X4[ci * 65 + idx];
            const float4 Di  = D4[ci * 65 + idx];
            const float4 Xk0 = X4[(k0 + 0) * 65 + idx];
            const float4 Xk1 = X4[(k0 + 1) * 65 + idx];
            const float4 Xk2 = X4[(k0 + 2) * 65 + idx];
            const float4 Dk0 = D4[(k0 + 0) * 65 + idx];
            const float4 Dk1 = D4[(k0 + 1) * 65 + idx];
            const float4 Dk2 = D4[(k0 + 2) * 65 + idx];

            float4 w, z;
            w.x = fmaf(-0.5f, Di.x, Xi.x);
            w.y = fmaf(-0.5f, Di.y, Xi.y);
            w.z = fmaf(-0.5f, Di.z, Xi.z);
            w.w = fmaf(-0.5f, Di.w, Xi.w);
            z.x = fmaf(-(1.0f / 3.0f), Di.x, 0.5f * Xi.x);
            z.y = fmaf(-(1.0f / 3.0f), Di.y, 0.5f * Xi.y);
            z.z = fmaf(-(1.0f / 3.0f), Di.z, 0.5f * Xi.z);
            z.w = fmaf(-(1.0f / 3.0f), Di.w, 0.5f * Xi.w);

            #pragma unroll
            for (int j = 0; j < 9; ++j) {
                const float4 dj = D4[j * 65 + idx];
                { const float uu = w.x * dj.x, vv = z.x * dj.x; s2a[j] += uu;
                  a[j][0] = fmaf(vv, Dk0.x, fmaf(-uu, Xk0.x, a[j][0]));
                  a[j][1] = fmaf(vv, Dk1.x, fmaf(-uu, Xk1.x, a[j][1]));
                  a[j][2] = fmaf(vv, Dk2.x, fmaf(-uu, Xk2.x, a[j][2])); }
                { const float uu = w.y * dj.y, vv = z.y * dj.y; s2a[j] += uu;
                  a[j][0] = fmaf(vv, Dk0.y, fmaf(-uu, Xk0.y, a[j][0]));
                  a[j][1] = fmaf(vv, Dk1.y, fmaf(-uu, Xk1.y, a[j][1]));
                  a[j][2] = fmaf(vv, Dk2.y, fmaf(-uu, Xk2.y, a[j][2])); }
                { const float uu = w.z * dj.z, vv = z.z * dj.z; s2a[j] += uu;
                  a[j][0] = fmaf(vv, Dk0.z, fmaf(-uu, Xk0.z, a[j][0]));
                  a[j][1] = fmaf(vv, Dk1.z, fmaf(-uu, Xk1.z, a[j][1]));
                  a[j][2] = fmaf(vv, Dk2.z, fmaf(-uu, Xk2.z, a[j][2])); }
                { const float uu = w.w * dj.w, vv = z.w * dj.w; s2a[j] += uu;
                  a[j][0] = fmaf(vv, Dk0.w, fmaf(-uu, Xk0.w, a[j][0]));
                  a[j][1] = fmaf(vv, Dk1.w, fmaf(-uu, Xk1.w, a[j][1]));
                  a[j][2] = fmaf(vv, Dk2.w, fmaf(-uu, Xk2.w, a[j][2])); }
            }
        }
    }
    __syncthreads();   // last table read above; dump may now alias tables

    // ---- dump partials (aliases dead tables) ----
    if (act) {
        float* pa = u + tid * ASTRIDE;
        #pragma unroll
        for (int j = 0; j < 9; ++j) {
            pa[j * 3 + 0] = a[j][0];
            pa[j * 3 + 1] = a[j][1];
            pa[j * 3 + 2] = a[j][2];
        }
        if (kt == 0) {
            float* ps = u + DUMPF + chunk * 81 + ci * 9;
            #pragma unroll
            for (int j = 0; j < 9; ++j) ps[j] = s2a[j];
        }
    }
    __syncthreads();

    // ---- combine s2 -> sig[9..89] ----
    if (tid < 81) {
        float s = 0.f;
        #pragma unroll
        for (int c = 0; c < NCHUNK; ++c) s += u[DUMPF + c * 81 + tid];
        sig[9 + tid] = s;
    }
    __syncthreads();

    // ---- combine s3 -> sig[90..818] (one element per thread) ----
    if (tid < 729) {
        const int e   = tid;
        const int i   = e / 81;
        const int r   = e - i * 81;
        const int j   = r / 9;
        const int k   = r - j * 9;
        const int ktv = k / 3;
        const int km  = k - ktv * 3;
        const int toff = (i * 3 + ktv) * ASTRIDE + j * 3 + km;
        float s = 0.f;
        #pragma unroll
        for (int c = 0; c < NCHUNK; ++c) s += u[c * CHSTR + toff];
        s = fmaf(sig[9 + i * 9 + j], sig[k], s);
        sig[90 + e] = s;
    }
    __syncthreads();

    // ---- linear: out[b][o] = bias[o] + sum_ch sig[ch]*Wg[ch][o] ----
    {
        const int oq = tid & 31;     // outputs 4*oq..4*oq+3
        const int sl = tid >> 5;     // channel slice 0..31
        float4 acc = make_float4(0.f, 0.f, 0.f, 0.f);
        const float4* Wq = (const float4*)Wg;
        for (int ch = sl; ch < 819; ch += 32) {
            const float s = sig[ch];
            const float4 wv = Wq[(size_t)ch * 32 + oq];
            acc.x = fmaf(s, wv.x, acc.x);
            acc.y = fmaf(s, wv.y, acc.y);
            acc.z = fmaf(s, wv.z, acc.z);
            acc.w = fmaf(s, wv.w, acc.w);
        }
        float4* pbuf = (float4*)u;               // aliases dead dump region
        pbuf[sl * 32 + oq] = acc;
    }
    __syncthreads();
    if (tid < 32) {
        const float4* pbuf = (const float4*)u;
        float4 r = pbuf[tid];
        #pragma unroll
        for (int s = 1; s < 32; ++s) {
            const float4 p = pbuf[s * 32 + tid];
            r.x += p.x; r.y += p.y; r.z += p.z; r.w += p.w;
        }
        const float4 bv = ((const float4*)bias)[tid];
        r.x += bv.x; r.y += bv.y; r.z += bv.z; r.w += bv.w;
        ((float4*)(out + (size_t)b * 128))[tid] = r;
    }
}

extern "C" void kernel_launch(void* const* d_in, const int* in_sizes, int n_in,
                              void* d_out, int out_size, void* d_ws, size_t ws_size,
                              hipStream_t stream) {
    const float* inp  = (const float*)d_in[0];
    const float* Wp   = (const float*)d_in[1];
    const float* bias = (const float*)d_in[2];
    float* outp = (float*)d_out;
    (void)in_sizes; (void)n_in; (void)out_size; (void)d_ws; (void)ws_size;

    hipLaunchKernelGGL(signet_fwd, dim3(256), dim3(1024), 0, stream,
                       inp, Wp, bias, outp);
}

// Round 9
// 44.615 us; speedup vs baseline: 1.2230x; 1.0160x over previous
//
#include <hip/hip_runtime.h>

// SigNet forward, closed-form (scan-free) depth-3 signature + Linear.
// B=256, L=256, CIN=8, C=9, SIG_CH=819, OUT=128.
//
// s1[i]       = x_L[i]
// s2[i][j]    = sum_l w_l[i] * d_l[j]                   w = X - 0.5*D
// s3[i][j][k] = s2[i][j]*x_L[k]
//             + sum_l ( z_l[i]*d_l[j]*d_l[k] - w_l[i]*d_l[j]*X_l[k] )
//   with z = 0.5*X - D/3       (X = absolute path value at segment end)
//
// One block per batch, 1024 threads. amdgpu_waves_per_eu(4,4) -> 128-VGPR
// budget (R7/R8's __launch_bounds__ kept a 64-VGPR cap and spilled the 36
// per-thread accumulators: 45+90 MB scratch traffic, 45-55 us). 16 waves/CU
// is the LDS limit anyway (114 KB -> 1 block/CU), so nothing is lost.

#define ROWF    260           // table row stride in floats (260%32==4)
#define NCHUNK  32
#define TPC     27
#define ASTRIDE 29
#define CHSTR   (TPC * ASTRIDE)                 // 783
#define DUMPF   (NCHUNK * CHSTR)                // 25056 floats
#define U1SZ    (DUMPF + NCHUNK * 81)           // 27648 floats = 110.6 KB

__global__
__attribute__((amdgpu_flat_work_group_size(1024, 1024), amdgpu_waves_per_eu(4, 4)))
void signet_fwd(
    const float* __restrict__ inp,   // [256, 256, 8]
    const float* __restrict__ Wg,    // [819, 128]
    const float* __restrict__ bias,  // [128]
    float* __restrict__ out)         // [256, 128]
{
    __shared__ float sig[820];
    __shared__ __align__(16) float u[U1SZ];

    float* Xt = u;                 // [9][ROWF]   (dead after main loop)
    float* Dt = u + 9 * ROWF;      // [9][ROWF]

    const int tid = threadIdx.x;
    const int b   = blockIdx.x;

    // ---- prep: tables (column t = segment t+1, basepoint 0) + s1 = x_L ----
    if (tid < 512) {
        const int t = tid & 255;
        const float* rc = inp + (size_t)b * 2048 + (size_t)t * 8;
        if (tid < 256) {
            float4 c0 = *(const float4*)rc;
            float4 p0 = make_float4(0.f, 0.f, 0.f, 0.f);
            float  tp = 0.f;
            if (t > 0) { p0 = *(const float4*)(rc - 8); tp = (float)(t - 1) * (1.0f / 255.0f); }
            float cur[5] = { (float)t * (1.0f / 255.0f), c0.x, c0.y, c0.z, c0.w };
            float prv[5] = { tp, p0.x, p0.y, p0.z, p0.w };
            #pragma unroll
            for (int c = 0; c < 5; ++c) {
                Xt[c * ROWF + t] = cur[c];
                Dt[c * ROWF + t] = cur[c] - prv[c];
            }
        } else {
            float4 c1 = *(const float4*)(rc + 4);
            float4 p1 = make_float4(0.f, 0.f, 0.f, 0.f);
            if (t > 0) p1 = *(const float4*)(rc - 4);
            float cur[4] = { c1.x, c1.y, c1.z, c1.w };
            float prv[4] = { p1.x, p1.y, p1.z, p1.w };
            #pragma unroll
            for (int c = 0; c < 4; ++c) {
                Xt[(5 + c) * ROWF + t] = cur[c];
                Dt[(5 + c) * ROWF + t] = cur[c] - prv[c];
            }
        }
    }
    if (tid < 9) {
        sig[tid] = (tid == 0) ? 1.0f
                              : inp[(size_t)b * 2048 + 255 * 8 + (tid - 1)];
    }
    __syncthreads();

    // ---- main: chunk = tid/27 handles float4 cols {2*chunk, 2*chunk+1} ----
    const int  chunk = tid / TPC;            // 0..37 (>=32 idle)
    const int  tloc  = tid - chunk * TPC;    // 0..26
    const int  ci    = tloc / 3;             // channel i
    const int  kt    = tloc - ci * 3;        // k-triple
    const bool act   = (chunk < NCHUNK);

    float a[9][3];
    float s2a[9];
    #pragma unroll
    for (int j = 0; j < 9; ++j) { s2a[j] = 0.f; a[j][0] = 0.f; a[j][1] = 0.f; a[j][2] = 0.f; }

    if (act) {
        const float4* X4 = (const float4*)u;             // [9][65]
        const float4* D4 = (const float4*)u + 9 * 65;
        const int k0 = 3 * kt;
        const int fb = chunk * 2;

        #pragma unroll
        for (int q = 0; q < 2; ++q) {
            const int idx = fb + q;
            const float4 Xi  = X4[ci * 65 + idx];
            const float4 Di  = D4[ci * 65 + idx];
            const float4 Xk0 = X4[(k0 + 0) * 65 + idx];
            const float4 Xk1 = X4[(k0 + 1) * 65 + idx];
            const float4 Xk2 = X4[(k0 + 2) * 65 + idx];
            const float4 Dk0 = D4[(k0 + 0) * 65 + idx];
            const float4 Dk1 = D4[(k0 + 1) * 65 + idx];
            const float4 Dk2 = D4[(k0 + 2) * 65 + idx];

            float4 w, z;
            w.x = fmaf(-0.5f, Di.x, Xi.x);
            w.y = fmaf(-0.5f, Di.y, Xi.y);
            w.z = fmaf(-0.5f, Di.z, Xi.z);
            w.w = fmaf(-0.5f, Di.w, Xi.w);
            z.x = fmaf(-(1.0f / 3.0f), Di.x, 0.5f * Xi.x);
            z.y = fmaf(-(1.0f / 3.0f), Di.y, 0.5f * Xi.y);
            z.z = fmaf(-(1.0f / 3.0f), Di.z, 0.5f * Xi.z);
            z.w = fmaf(-(1.0f / 3.0f), Di.w, 0.5f * Xi.w);

            #pragma unroll
            for (int j = 0; j < 9; ++j) {
                const float4 dj = D4[j * 65 + idx];
                { const float uu = w.x * dj.x, vv = z.x * dj.x; s2a[j] += uu;
                  a[j][0] = fmaf(vv, Dk0.x, fmaf(-uu, Xk0.x, a[j][0]));
                  a[j][1] = fmaf(vv, Dk1.x, fmaf(-uu, Xk1.x, a[j][1]));
                  a[j][2] = fmaf(vv, Dk2.x, fmaf(-uu, Xk2.x, a[j][2])); }
                { const float uu = w.y * dj.y, vv = z.y * dj.y; s2a[j] += uu;
                  a[j][0] = fmaf(vv, Dk0.y, fmaf(-uu, Xk0.y, a[j][0]));
                  a[j][1] = fmaf(vv, Dk1.y, fmaf(-uu, Xk1.y, a[j][1]));
                  a[j][2] = fmaf(vv, Dk2.y, fmaf(-uu, Xk2.y, a[j][2])); }
                { const float uu = w.z * dj.z, vv = z.z * dj.z; s2a[j] += uu;
                  a[j][0] = fmaf(vv, Dk0.z, fmaf(-uu, Xk0.z, a[j][0]));
                  a[j][1] = fmaf(vv, Dk1.z, fmaf(-uu, Xk1.z, a[j][1]));
                  a[j][2] = fmaf(vv, Dk2.z, fmaf(-uu, Xk2.z, a[j][2])); }
                { const float uu = w.w * dj.w, vv = z.w * dj.w; s2a[j] += uu;
                  a[j][0] = fmaf(vv, Dk0.w, fmaf(-uu, Xk0.w, a[j][0]));
                  a[j][1] = fmaf(vv, Dk1.w, fmaf(-uu, Xk1.w, a[j][1]));
                  a[j][2] = fmaf(vv, Dk2.w, fmaf(-uu, Xk2.w, a[j][2])); }
            }
        }
    }
    __syncthreads();   // last table read above; dump may now alias tables

    // ---- dump partials (aliases dead tables) ----
    if (act) {
        float* pa = u + tid * ASTRIDE;
        #pragma unroll
        for (int j = 0; j < 9; ++j) {
            pa[j * 3 + 0] = a[j][0];
            pa[j * 3 + 1] = a[j][1];
            pa[j * 3 + 2] = a[j][2];
        }
        if (kt == 0) {
            float* ps = u + DUMPF + chunk * 81 + ci * 9;
            #pragma unroll
            for (int j = 0; j < 9; ++j) ps[j] = s2a[j];
        }
    }
    __syncthreads();

    // ---- combine s2 -> sig[9..89] ----
    if (tid < 81) {
        float s = 0.f;
        #pragma unroll
        for (int c = 0; c < NCHUNK; ++c) s += u[DUMPF + c * 81 + tid];
        sig[9 + tid] = s;
    }
    __syncthreads();

    // ---- combine s3 -> sig[90..818] (one element per thread) ----
    if (tid < 729) {
        const int e   = tid;
        const int i   = e / 81;
        const int r   = e - i * 81;
        const int j   = r / 9;
        const int k   = r - j * 9;
        const int ktv = k / 3;
        const int km  = k - ktv * 3;
        const int toff = (i * 3 + ktv) * ASTRIDE + j * 3 + km;
        float s = 0.f;
        #pragma unroll
        for (int c = 0; c < NCHUNK; ++c) s += u[c * CHSTR + toff];
        s = fmaf(sig[9 + i * 9 + j], sig[k], s);
        sig[90 + e] = s;
    }
    __syncthreads();

    // ---- linear: out[b][o] = bias[o] + sum_ch sig[ch]*Wg[ch][o] ----
    {
        const int oq = tid & 31;     // outputs 4*oq..4*oq+3
        const int sl = tid >> 5;     // channel slice 0..31
        float4 acc = make_float4(0.f, 0.f, 0.f, 0.f);
        const float4* Wq = (const float4*)Wg;
        for (int ch = sl; ch < 819; ch += 32) {
            const float s = sig[ch];
            const float4 wv = Wq[(size_t)ch * 32 + oq];
            acc.x = fmaf(s, wv.x, acc.x);
            acc.y = fmaf(s, wv.y, acc.y);
            acc.z = fmaf(s, wv.z, acc.z);
            acc.w = fmaf(s, wv.w, acc.w);
        }
        float4* pbuf = (float4*)u;               // aliases dead dump region
        pbuf[sl * 32 + oq] = acc;
    }
    __syncthreads();
    if (tid < 32) {
        const float4* pbuf = (const float4*)u;
        float4 r = pbuf[tid];
        #pragma unroll
        for (int s = 1; s < 32; ++s) {
            const float4 p = pbuf[s * 32 + tid];
            r.x += p.x; r.y += p.y; r.z += p.z; r.w += p.w;
        }
        const float4 bv = ((const float4*)bias)[tid];
        r.x += bv.x; r.y += bv.y; r.z += bv.z; r.w += bv.w;
        ((float4*)(out + (size_t)b * 128))[tid] = r;
    }
}

extern "C" void kernel_launch(void* const* d_in, const int* in_sizes, int n_in,
                              void* d_out, int out_size, void* d_ws, size_t ws_size,
                              hipStream_t stream) {
    const float* inp  = (const float*)d_in[0];
    const float* Wp   = (const float*)d_in[1];
    const float* bias = (const float*)d_in[2];
    float* outp = (float*)d_out;
    (void)in_sizes; (void)n_in; (void)out_size; (void)d_ws; (void)ws_size;

    hipLaunchKernelGGL(signet_fwd, dim3(256), dim3(1024), 0, stream,
                       inp, Wp, bias, outp);
}

// Round 10
// 17.460 us; speedup vs baseline: 3.1251x; 2.5552x over previous
//
#include <hip/hip_runtime.h>

// SigNet forward, closed-form (scan-free) depth-3 signature + Linear.
// B=256, L=256, CIN=8, C=9, SIG_CH=819, OUT=128.
//
// s1[i]       = x_L[i]
// s2[i][j]    = sum_l w_l[i] * d_l[j]                   w = X - 0.5*D
// s3[i][j][k] = s2[i][j]*x_L[k]
//             + sum_l ( z_l[i]*d_l[j]*d_l[k] - w_l[i]*d_l[j]*X_l[k] )
//   with z = 0.5*X - D/3       (X = absolute path value at segment end)
//
// 1024 threads/block, one block per batch. At 1024-thread workgroups the
// compiler pins a 64-VGPR budget (R7-R9 evidence), so per-thread state is
// sized for it: ownership (i, j-triple, k-triple) -> 81 threads per l-range,
// 8 ranges = 648 active, only 12 accumulators/thread. No spill by design.

#define RANGES  8
#define TPR     81
#define NACT    (RANGES * TPR)        // 648
#define PSTR    13                    // dump stride (odd -> conflict-free)
#define U1SZ    (NACT * PSTR)         // 8424 floats; tables (4680) alias front

__global__ __launch_bounds__(1024) void signet_fwd(
    const float* __restrict__ inp,   // [256, 256, 8]
    const float* __restrict__ Wg,    // [819, 128]
    const float* __restrict__ bias,  // [128]
    float* __restrict__ out)         // [256, 128]
{
    __shared__ float sig[820];
    __shared__ __align__(16) float u[U1SZ];

    float* Xt = u;                 // [9][260] floats (dead after main loop)
    float* Dt = u + 9 * 260;

    const int tid = threadIdx.x;
    const int b   = blockIdx.x;

    // ---- prep: tables (column t = segment t+1, basepoint 0) + s1 = x_L ----
    if (tid < 512) {
        const int t = tid & 255;
        const float* rc = inp + (size_t)b * 2048 + (size_t)t * 8;
        if (tid < 256) {
            float4 c0 = *(const float4*)rc;
            float4 p0 = make_float4(0.f, 0.f, 0.f, 0.f);
            float  tp = 0.f;
            if (t > 0) { p0 = *(const float4*)(rc - 8); tp = (float)(t - 1) * (1.0f / 255.0f); }
            float cur[5] = { (float)t * (1.0f / 255.0f), c0.x, c0.y, c0.z, c0.w };
            float prv[5] = { tp, p0.x, p0.y, p0.z, p0.w };
            #pragma unroll
            for (int c = 0; c < 5; ++c) {
                Xt[c * 260 + t] = cur[c];
                Dt[c * 260 + t] = cur[c] - prv[c];
            }
        } else {
            float4 c1 = *(const float4*)(rc + 4);
            float4 p1 = make_float4(0.f, 0.f, 0.f, 0.f);
            if (t > 0) p1 = *(const float4*)(rc - 4);
            float cur[4] = { c1.x, c1.y, c1.z, c1.w };
            float prv[4] = { p1.x, p1.y, p1.z, p1.w };
            #pragma unroll
            for (int c = 0; c < 4; ++c) {
                Xt[(5 + c) * 260 + t] = cur[c];
                Dt[(5 + c) * 260 + t] = cur[c] - prv[c];
            }
        }
    }
    if (tid < 9) {
        sig[tid] = (tid == 0) ? 1.0f
                              : inp[(size_t)b * 2048 + 255 * 8 + (tid - 1)];
    }
    __syncthreads();

    // ---- main: range rr = tid/81 handles float4 cols [rr*8, rr*8+8) ----
    const bool act = (tid < NACT);
    const int  rr  = tid / TPR;
    const int  lt  = tid - rr * TPR;     // 0..80
    const int  ii  = lt / 9;             // channel i
    const int  jk  = lt - ii * 9;
    const int  jt  = jk / 3;             // j-triple: j = 3*jt+jm
    const int  kt  = jk - jt * 3;        // k-triple: k = 3*kt+km

    float a[3][3];                       // [jm][km]
    float s2a[3];
    #pragma unroll
    for (int jm = 0; jm < 3; ++jm) {
        s2a[jm] = 0.f;
        a[jm][0] = 0.f; a[jm][1] = 0.f; a[jm][2] = 0.f;
    }

    if (act) {
        const float4* X4 = (const float4*)u;             // [9][65]
        const float4* D4 = (const float4*)u + 9 * 65;

        #pragma unroll
        for (int q = 0; q < 8; ++q) {
            const int idx = rr * 8 + q;
            const float4 Xi = X4[ii * 65 + idx];
            const float4 Di = D4[ii * 65 + idx];
            float4 w, z;
            w.x = fmaf(-0.5f, Di.x, Xi.x);
            w.y = fmaf(-0.5f, Di.y, Xi.y);
            w.z = fmaf(-0.5f, Di.z, Xi.z);
            w.w = fmaf(-0.5f, Di.w, Xi.w);
            z.x = fmaf(-(1.0f / 3.0f), Di.x, 0.5f * Xi.x);
            z.y = fmaf(-(1.0f / 3.0f), Di.y, 0.5f * Xi.y);
            z.z = fmaf(-(1.0f / 3.0f), Di.z, 0.5f * Xi.z);
            z.w = fmaf(-(1.0f / 3.0f), Di.w, 0.5f * Xi.w);

            float4 uu[3], vv[3];
            #pragma unroll
            for (int jm = 0; jm < 3; ++jm) {
                const float4 Dj = D4[(3 * jt + jm) * 65 + idx];
                uu[jm].x = w.x * Dj.x;  uu[jm].y = w.y * Dj.y;
                uu[jm].z = w.z * Dj.z;  uu[jm].w = w.w * Dj.w;
                vv[jm].x = z.x * Dj.x;  vv[jm].y = z.y * Dj.y;
                vv[jm].z = z.z * Dj.z;  vv[jm].w = z.w * Dj.w;
                s2a[jm] += (uu[jm].x + uu[jm].y) + (uu[jm].z + uu[jm].w);
            }
            #pragma unroll
            for (int km = 0; km < 3; ++km) {
                const float4 Xk = X4[(3 * kt + km) * 65 + idx];
                const float4 Dk = D4[(3 * kt + km) * 65 + idx];
                #pragma unroll
                for (int jm = 0; jm < 3; ++jm) {
                    a[jm][km] = fmaf(vv[jm].x, Dk.x, fmaf(-uu[jm].x, Xk.x, a[jm][km]));
                    a[jm][km] = fmaf(vv[jm].y, Dk.y, fmaf(-uu[jm].y, Xk.y, a[jm][km]));
                    a[jm][km] = fmaf(vv[jm].z, Dk.z, fmaf(-uu[jm].z, Xk.z, a[jm][km]));
                    a[jm][km] = fmaf(vv[jm].w, Dk.w, fmaf(-uu[jm].w, Xk.w, a[jm][km]));
                }
            }
        }
    }
    __syncthreads();   // last table read above; dump may now alias tables

    // ---- dump partials (12 floats/thread, stride 13) ----
    if (act) {
        float* pa = u + tid * PSTR;
        #pragma unroll
        for (int jm = 0; jm < 3; ++jm) {
            pa[jm * 3 + 0] = a[jm][0];
            pa[jm * 3 + 1] = a[jm][1];
            pa[jm * 3 + 2] = a[jm][2];
        }
        pa[9]  = s2a[0];
        pa[10] = s2a[1];
        pa[11] = s2a[2];
    }
    __syncthreads();

    // ---- combine s2 -> sig[9..89] ----
    if (tid < 81) {
        const int i2  = tid / 9;
        const int j2  = tid - i2 * 9;
        const int jt2 = j2 / 3;
        const int jm2 = j2 - jt2 * 3;
        const int base = (i2 * 9 + jt2 * 3) * PSTR + 9 + jm2;   // kt == 0 thread
        float s = 0.f;
        #pragma unroll
        for (int c = 0; c < RANGES; ++c) s += u[c * TPR * PSTR + base];
        sig[9 + tid] = s;
    }
    __syncthreads();

    // ---- combine s3 -> sig[90..818] (one element per thread) ----
    if (tid < 729) {
        const int i3  = tid / 81;
        const int rem = tid - i3 * 81;
        const int j3  = rem / 9;
        const int k3  = rem - j3 * 9;
        const int jt3 = j3 / 3, jm3 = j3 - jt3 * 3;
        const int kt3 = k3 / 3, km3 = k3 - kt3 * 3;
        const int base = (i3 * 9 + jt3 * 3 + kt3) * PSTR + jm3 * 3 + km3;
        float s = 0.f;
        #pragma unroll
        for (int c = 0; c < RANGES; ++c) s += u[c * TPR * PSTR + base];
        s = fmaf(sig[9 + i3 * 9 + j3], sig[k3], s);
        sig[90 + tid] = s;
    }
    __syncthreads();

    // ---- linear: out[b][o] = bias[o] + sum_ch sig[ch]*Wg[ch][o] ----
    {
        const int oq = tid & 31;     // outputs 4*oq..4*oq+3
        const int sl = tid >> 5;     // channel slice 0..31
        float4 acc = make_float4(0.f, 0.f, 0.f, 0.f);
        const float4* Wq = (const float4*)Wg;
        for (int ch = sl; ch < 819; ch += 32) {
            const float s = sig[ch];
            const float4 wv = Wq[(size_t)ch * 32 + oq];
            acc.x = fmaf(s, wv.x, acc.x);
            acc.y = fmaf(s, wv.y, acc.y);
            acc.z = fmaf(s, wv.z, acc.z);
            acc.w = fmaf(s, wv.w, acc.w);
        }
        float4* pbuf = (float4*)u;               // aliases dead dump region
        pbuf[sl * 32 + oq] = acc;
    }
    __syncthreads();
    if (tid < 32) {
        const float4* pbuf = (const float4*)u;
        float4 r = pbuf[tid];
        #pragma unroll
        for (int s = 1; s < 32; ++s) {
            const float4 p = pbuf[s * 32 + tid];
            r.x += p.x; r.y += p.y; r.z += p.z; r.w += p.w;
        }
        const float4 bv = ((const float4*)bias)[tid];
        r.x += bv.x; r.y += bv.y; r.z += bv.z; r.w += bv.w;
        ((float4*)(out + (size_t)b * 128))[tid] = r;
    }
}

extern "C" void kernel_launch(void* const* d_in, const int* in_sizes, int n_in,
                              void* d_out, int out_size, void* d_ws, size_t ws_size,
                              hipStream_t stream) {
    const float* inp  = (const float*)d_in[0];
    const float* Wp   = (const float*)d_in[1];
    const float* bias = (const float*)d_in[2];
    float* outp = (float*)d_out;
    (void)in_sizes; (void)n_in; (void)out_size; (void)d_ws; (void)ws_size;

    hipLaunchKernelGGL(signet_fwd, dim3(256), dim3(1024), 0, stream,
                       inp, Wp, bias, outp);
}